// Round 4
// baseline (485.280 us; speedup 1.0000x reference)
//
#include <hip/hip_runtime.h>

#define HH 64
#define VV 50257
#define BB 32
#define LL 4096

constexpr float LN_EPS_F = 1e-5f;
constexpr float DELTA_EPS_F = 1e-6f;

constexpr int CS = 64;       // chunk size (steps per chunk)
constexpr int NG = LL / CS;  // 64 chunks per batch

// ---------------- DPP wave reduction (sum of 64 lanes -> lane 63) ----------------
template <int CTRL>
__device__ __forceinline__ float dpp_add(float x) {
  int t = __builtin_amdgcn_update_dpp(0, __float_as_int(x), CTRL, 0xF, 0xF, true);
  return x + __int_as_float(t);
}

__device__ __forceinline__ float wave_sum_lane63(float x) {
  x = dpp_add<0x111>(x);  // row_shr:1
  x = dpp_add<0x112>(x);  // row_shr:2
  x = dpp_add<0x114>(x);  // row_shr:4
  x = dpp_add<0x118>(x);  // row_shr:8
  x = dpp_add<0x142>(x);  // row_bcast:15
  x = dpp_add<0x143>(x);  // row_bcast:31
  return x;               // lane 63 holds the full sum
}

__device__ __forceinline__ float readlane_f(float x, int lane) {
  return __int_as_float(__builtin_amdgcn_readlane(__float_as_int(x), lane));
}

// ---------------- Kernel 0: transpose w1 -> w1T[j][h] ----------------
__global__ __launch_bounds__(256) void prep_kernel(const float* __restrict__ w1,
                                                   float* __restrict__ w1T) {
  int i = blockIdx.x * 256 + threadIdx.x;  // 8192 elements
  int h = i >> 7, j = i & 127;             // w1[h][j], h<64, j<128
  w1T[j * HH + h] = w1[i];
}

// ---------------- Kernel 1: encoder — weight broadcast via readlane ----------
// 2 tokens per thread; weights streamed per-16-jj group into lane-distributed
// VGPRs, broadcast with v_readlane (no s_load stalls, no LDS pipe).
// VGPR budget ~310 -> (256,1) gives 512 cap, one block (4 waves) per CU.
__global__ __launch_bounds__(256, 1) void encoder_kernel(
    const int* __restrict__ seq, const float* __restrict__ embed,
    const float* __restrict__ w1T, const float* __restrict__ b1,
    const float* __restrict__ w2, const float* __restrict__ b2,
    const float* __restrict__ ln_g, const float* __restrict__ ln_b,
    float* __restrict__ h_all, float* __restrict__ beta) {
  int tid = threadIdx.x, lane = tid & 63;
  int n0 = blockIdx.x * 512 + tid;
  int n1 = n0 + 256;
  int s0 = seq[n0], s1 = seq[n1];

  float e0[HH], e1[HH];
  {
    const float4* p0 = reinterpret_cast<const float4*>(embed + (size_t)s0 * HH);
    const float4* p1 = reinterpret_cast<const float4*>(embed + (size_t)s1 * HH);
#pragma unroll
    for (int i = 0; i < 16; ++i) {
      float4 v0 = p0[i], v1 = p1[i];
      e0[4 * i + 0] = v0.x; e0[4 * i + 1] = v0.y; e0[4 * i + 2] = v0.z; e0[4 * i + 3] = v0.w;
      e1[4 * i + 0] = v1.x; e1[4 * i + 1] = v1.y; e1[4 * i + 2] = v1.z; e1[4 * i + 3] = v1.w;
    }
  }

  // lane-held copies of small vectors (broadcast later via readlane)
  float b1v0 = b1[lane], b1v1 = b1[HH + lane];
  float b2v = b2[lane];
  float gv = ln_g[lane], lbv = ln_b[lane];

  float a0[HH], a1[HH];
#pragma unroll
  for (int h = 0; h < HH; ++h) {
    float t = readlane_f(b2v, h);
    a0[h] = t; a1[h] = t;
  }

#pragma unroll 1
  for (int g = 0; g < 8; ++g) {  // 16 jj per group
    float w1g[16], w2g[16];
#pragma unroll
    for (int u = 0; u < 16; ++u) {
      w1g[u] = w1T[(g * 16 + u) * HH + lane];
      w2g[u] = w2[(g * 16 + u) * HH + lane];
    }
    float bsrc = (g < 4) ? b1v0 : b1v1;
#pragma unroll
    for (int u = 0; u < 16; ++u) {
      float d00 = 0.f, d01 = 0.f, d10 = 0.f, d11 = 0.f;
#pragma unroll
      for (int h = 0; h < HH; h += 2) {
        float wa = readlane_f(w1g[u], h);
        float wb = readlane_f(w1g[u], h + 1);
        d00 = fmaf(e0[h], wa, d00); d01 = fmaf(e0[h + 1], wb, d01);
        d10 = fmaf(e1[h], wa, d10); d11 = fmaf(e1[h + 1], wb, d11);
      }
      float bb = readlane_f(bsrc, (g * 16 + u) & 63);
      float h0 = fmaxf(d00 + d01 + bb, 0.f);
      float h1 = fmaxf(d10 + d11 + bb, 0.f);
#pragma unroll
      for (int h = 0; h < HH; h += 2) {
        float wa = readlane_f(w2g[u], h);
        float wb = readlane_f(w2g[u], h + 1);
        a0[h] = fmaf(h0, wa, a0[h]); a0[h + 1] = fmaf(h0, wb, a0[h + 1]);
        a1[h] = fmaf(h1, wa, a1[h]); a1[h + 1] = fmaf(h1, wb, a1[h + 1]);
      }
    }
  }

  // residual + LN + beta for both tokens
#pragma unroll 1
  for (int tok = 0; tok < 2; ++tok) {
    float* a = tok ? a1 : a0;
    float* e = tok ? e1 : e0;
    int n = tok ? n1 : n0;
    float sum = 0.f;
#pragma unroll
    for (int h = 0; h < HH; ++h) { a[h] += e[h]; sum += a[h]; }
    float mu = sum * (1.f / HH);
    float vs = 0.f;
#pragma unroll
    for (int h = 0; h < HH; ++h) { float dx = a[h] - mu; vs = fmaf(dx, dx, vs); }
    float rstd = rsqrtf(vs * (1.f / HH) + LN_EPS_F);

    float ss = 0.f;
    float4* hp = reinterpret_cast<float4*>(h_all + (size_t)n * HH);
#pragma unroll
    for (int i = 0; i < 16; ++i) {
      float4 o;
      o.x = fmaf((a[4 * i + 0] - mu) * rstd, readlane_f(gv, 4 * i + 0), readlane_f(lbv, 4 * i + 0));
      o.y = fmaf((a[4 * i + 1] - mu) * rstd, readlane_f(gv, 4 * i + 1), readlane_f(lbv, 4 * i + 1));
      o.z = fmaf((a[4 * i + 2] - mu) * rstd, readlane_f(gv, 4 * i + 2), readlane_f(lbv, 4 * i + 2));
      o.w = fmaf((a[4 * i + 3] - mu) * rstd, readlane_f(gv, 4 * i + 3), readlane_f(lbv, 4 * i + 3));
      ss = fmaf(o.x, o.x, ss); ss = fmaf(o.y, o.y, ss);
      ss = fmaf(o.z, o.z, ss); ss = fmaf(o.w, o.w, ss);
      hp[i] = o;
    }
    beta[n] = 1.f / (ss + DELTA_EPS_F);
  }
}

// ---------------- Kernel 2 (phase 1): per-chunk transform matrices ----------------
// A_c = prod_t (I - beta_t k_t k_t^T), lane = column. K-tile vector-loaded
// lane-distributed (reg=t, lane=h); k[h] broadcast via readlane — no s_load,
// no LDS. 8-step groups keep code + VGPRs small.
constexpr int KG = 8;

__global__ __launch_bounds__(64, 2) void chunk_mat_kernel(
    const float* __restrict__ h_all, const float* __restrict__ beta,
    float* __restrict__ A_g) {
  int c = blockIdx.x, b = blockIdx.y, lane = threadIdx.x;
  const float* hb = h_all + (size_t)b * LL * HH;

  float A[HH];
#pragma unroll
  for (int h = 0; h < HH; ++h) A[h] = (h == lane) ? 1.f : 0.f;

  float bvv = beta[(size_t)b * LL + c * CS + lane];  // lane i holds beta_{cCS+i}

  const float* kbase = hb + (size_t)c * CS * HH + lane;
  float Ktg[KG], Ktn[KG];
  {  // load top group (local steps 56..63)
    const float* gp = kbase + (size_t)(CS - KG) * HH;
#pragma unroll
    for (int u = 0; u < KG; ++u) Ktg[u] = gp[u * HH];
    if (c == NG - 1) Ktg[KG - 1] = 0.f;  // t = L-1 is q's slot: k=0 => identity step
  }

#pragma unroll 1
  for (int g = CS / KG - 1; g >= 0; --g) {
    if (g > 0) {  // prefetch next-lower group
      const float* gp = kbase + (size_t)(g - 1) * KG * HH;
#pragma unroll
      for (int u = 0; u < KG; ++u) Ktn[u] = gp[u * HH];
    }
#pragma unroll
    for (int u = KG - 1; u >= 0; --u) {
      float d0 = 0.f, d1 = 0.f, d2 = 0.f, d3 = 0.f;
#pragma unroll
      for (int h = 0; h < HH; h += 4) {
        d0 = fmaf(readlane_f(Ktg[u], h + 0), A[h + 0], d0);
        d1 = fmaf(readlane_f(Ktg[u], h + 1), A[h + 1], d1);
        d2 = fmaf(readlane_f(Ktg[u], h + 2), A[h + 2], d2);
        d3 = fmaf(readlane_f(Ktg[u], h + 3), A[h + 3], d3);
      }
      float d = (d0 + d1) + (d2 + d3);
      float bd = -readlane_f(bvv, g * KG + u) * d;
#pragma unroll
      for (int h = 0; h < HH; ++h)
        A[h] = fmaf(bd, readlane_f(Ktg[u], h), A[h]);
    }
#pragma unroll
    for (int u = 0; u < KG; ++u) Ktg[u] = Ktn[u];
  }

  float* Ag = A_g + ((size_t)b * NG + c) * HH * HH;
#pragma unroll
  for (int h = 0; h < HH; ++h) Ag[(size_t)h * HH + lane] = A[h];  // coalesced rows
}

// ---------------- Kernel 3 (phase 2): chunk-boundary propagation ----------------
// Q_{NG-1} = q; store Q_c then Q_{c-1} = A_c Q_c. One wave per batch; lane = row.
__global__ __launch_bounds__(64, 1) void boundary_kernel(
    const float* __restrict__ h_all, const float* __restrict__ A_g,
    const int* __restrict__ read_pos_p, float* __restrict__ Qg) {
  int b = blockIdx.x, lane = threadIdx.x;
  int rpv = read_pos_p[0];
  int pos = rpv < 0 ? rpv + LL : rpv;

  float Q = h_all[((size_t)b * LL + pos) * HH + lane];

  const float* Ab = A_g + (size_t)b * NG * HH * HH + (size_t)lane * HH;

  float4 cur[16], nxt[16], nx2[16];
  {
    const float4* p = reinterpret_cast<const float4*>(Ab + (size_t)(NG - 1) * HH * HH);
#pragma unroll
    for (int i = 0; i < 16; ++i) cur[i] = p[i];
  }
  {
    const float4* p = reinterpret_cast<const float4*>(Ab + (size_t)(NG - 2) * HH * HH);
#pragma unroll
    for (int i = 0; i < 16; ++i) nxt[i] = p[i];
  }

#pragma unroll 1
  for (int c = NG - 1; c >= 0; --c) {
    if (c >= 2) {  // prefetch two chunks ahead
      const float4* p = reinterpret_cast<const float4*>(Ab + (size_t)(c - 2) * HH * HH);
#pragma unroll
      for (int i = 0; i < 16; ++i) nx2[i] = p[i];
    }
    Qg[((size_t)b * NG + c) * HH + lane] = Q;
    float a0 = 0.f, a1 = 0.f, a2 = 0.f, a3 = 0.f;
#pragma unroll
    for (int i = 0; i < 16; ++i) {
      a0 = fmaf(readlane_f(Q, 4 * i + 0), cur[i].x, a0);
      a1 = fmaf(readlane_f(Q, 4 * i + 1), cur[i].y, a1);
      a2 = fmaf(readlane_f(Q, 4 * i + 2), cur[i].z, a2);
      a3 = fmaf(readlane_f(Q, 4 * i + 3), cur[i].w, a3);
    }
    Q = (a0 + a1) + (a2 + a3);
#pragma unroll
    for (int i = 0; i < 16; ++i) { cur[i] = nxt[i]; nxt[i] = nx2[i]; }
  }
}

// ---------------- Kernel 4 (phase 3): parallel within-chunk r accumulation -------
__global__ __launch_bounds__(64, 1) void chunk_scan_kernel(
    const float* __restrict__ h_all, const float* __restrict__ beta,
    const float* __restrict__ Qg, float* __restrict__ rc) {
  int c = blockIdx.x, b = blockIdx.y, j = threadIdx.x;
  const float* hb = h_all + (size_t)b * LL * HH;
  const float* betab = beta + (size_t)b * LL;

  float P = Qg[((size_t)b * NG + c) * HH + j];
  float r = 0.f;

  float kk[CS];
#pragma unroll
  for (int i = 0; i < CS; ++i) kk[i] = hb[((size_t)(c * CS + i)) * HH + j];
  float bv = betab[c * CS + j];  // lane j holds beta_{cCS+j}

  bool last = (c == NG - 1);
#pragma unroll
  for (int i = CS - 1; i >= 0; --i) {
    float k = kk[i];
    float bt = readlane_f(bv, i);
    float m = k * P;
    float s = wave_sum_lane63(m);
    float d = readlane_f(s, 63);
    if (i == CS - 1 && last) d = 0.f;  // mask t = L-1
    r = fmaf(d, k, r);
    P = fmaf(-(bt * d), k, P);
  }
  rc[((size_t)b * NG + c) * HH + j] = r;
}

// ---------------- Kernel 5: combine r over chunks, y = r @ rp_w + rp_b ----------
__global__ __launch_bounds__(64, 1) void combine_kernel(
    const float* __restrict__ rc, const float* __restrict__ rp_w,
    const float* __restrict__ rp_b, float* __restrict__ yv) {
  int b = blockIdx.x, j = threadIdx.x;
  float r = 0.f;
#pragma unroll 8
  for (int cc = 0; cc < NG; ++cc) r += rc[((size_t)b * NG + cc) * HH + j];
  __shared__ float rs[HH];
  rs[j] = r;
  __syncthreads();
  float yj = rp_b[j];
#pragma unroll
  for (int h = 0; h < HH; ++h) yj = fmaf(rs[h], rp_w[h * HH + j], yj);
  yv[b * HH + j] = yj;
}

// ---------------- Kernel 6: output GEMM ----------------
__global__ __launch_bounds__(256, 2) void out_kernel(
    const float* __restrict__ yv, const float* __restrict__ out_w,
    const float* __restrict__ out_b, float* __restrict__ out) {
  __shared__ float ys[BB * HH];
  for (int i = threadIdx.x; i < BB * HH; i += 256) ys[i] = yv[i];
  __syncthreads();

  int v = blockIdx.x * 256 + threadIdx.x;
  if (v >= VV) return;

  float acc[BB];
  float ob = out_b[v];
#pragma unroll
  for (int b = 0; b < BB; ++b) acc[b] = ob;

  for (int h = 0; h < HH; ++h) {
    float w = out_w[(size_t)h * VV + v];
#pragma unroll
    for (int b = 0; b < BB; ++b) acc[b] = fmaf(ys[b * HH + h], w, acc[b]);
  }
#pragma unroll
  for (int b = 0; b < BB; ++b) out[(size_t)b * VV + v] = acc[b];
}

// ---------------- launch ----------------
extern "C" void kernel_launch(void* const* d_in, const int* in_sizes, int n_in,
                              void* d_out, int out_size, void* d_ws, size_t ws_size,
                              hipStream_t stream) {
  (void)in_sizes; (void)n_in; (void)out_size; (void)ws_size;
  const int*   seq   = (const int*)d_in[0];
  const int*   rp    = (const int*)d_in[1];
  const float* embed = (const float*)d_in[2];
  const float* w1    = (const float*)d_in[3];
  const float* b1    = (const float*)d_in[4];
  const float* w2    = (const float*)d_in[5];
  const float* b2    = (const float*)d_in[6];
  const float* ln_g  = (const float*)d_in[7];
  const float* ln_b  = (const float*)d_in[8];
  const float* rp_w  = (const float*)d_in[9];
  const float* rp_b  = (const float*)d_in[10];
  const float* out_w = (const float*)d_in[11];
  const float* out_b = (const float*)d_in[12];
  float* out = (float*)d_out;

  // workspace layout (~68.7 MB)
  float* h_all = (float*)d_ws;                               // B*L*H
  float* beta  = h_all + (size_t)BB * LL * HH;               // B*L
  float* A_g   = beta + (size_t)BB * LL;                     // B*NG*H*H
  float* Qg    = A_g + (size_t)BB * NG * HH * HH;            // B*NG*H
  float* rcv   = Qg + (size_t)BB * NG * HH;                  // B*NG*H
  float* yv    = rcv + (size_t)BB * NG * HH;                 // B*H
  float* w1T   = yv + (size_t)BB * HH;                       // 2H*H

  prep_kernel<<<32, 256, 0, stream>>>(w1, w1T);
  encoder_kernel<<<BB * LL / 512, 256, 0, stream>>>(seq, embed, w1T, b1, w2, b2,
                                                    ln_g, ln_b, h_all, beta);
  chunk_mat_kernel<<<dim3(NG, BB), 64, 0, stream>>>(h_all, beta, A_g);
  boundary_kernel<<<BB, 64, 0, stream>>>(h_all, A_g, rp, Qg);
  chunk_scan_kernel<<<dim3(NG, BB), 64, 0, stream>>>(h_all, beta, Qg, rcv);
  combine_kernel<<<BB, 64, 0, stream>>>(rcv, rp_w, rp_b, yv);
  out_kernel<<<(VV + 255) / 256, 256, 0, stream>>>(yv, out_w, out_b, out);
}

// Round 5
// 277.259 us; speedup vs baseline: 1.7503x; 1.7503x over previous
//
#include <hip/hip_runtime.h>

#define HH 64
#define VV 50257
#define BB 32
#define LL 4096

constexpr float LN_EPS_F = 1e-5f;
constexpr float DELTA_EPS_F = 1e-6f;

constexpr int CS = 64;       // chunk size (steps per chunk)
constexpr int NG = LL / CS;  // 64 chunks per batch

typedef float f32x4 __attribute__((ext_vector_type(4)));
typedef short bf16x8 __attribute__((ext_vector_type(8)));
union U16x8 { uint4 u; bf16x8 v; unsigned short s[8]; };

__device__ __forceinline__ unsigned short f2bf(float f) {
  union { float f; unsigned u; } v; v.f = f;
  unsigned r = v.u + 0x7fff + ((v.u >> 16) & 1);  // RNE
  return (unsigned short)(r >> 16);
}

// ---------------- DPP wave reduction (sum of 64 lanes -> lane 63) ----------------
template <int CTRL>
__device__ __forceinline__ float dpp_add(float x) {
  int t = __builtin_amdgcn_update_dpp(0, __float_as_int(x), CTRL, 0xF, 0xF, true);
  return x + __int_as_float(t);
}

__device__ __forceinline__ float wave_sum_lane63(float x) {
  x = dpp_add<0x111>(x);
  x = dpp_add<0x112>(x);
  x = dpp_add<0x114>(x);
  x = dpp_add<0x118>(x);
  x = dpp_add<0x142>(x);
  x = dpp_add<0x143>(x);
  return x;
}

__device__ __forceinline__ float readlane_f(float x, int lane) {
  return __int_as_float(__builtin_amdgcn_readlane(__float_as_int(x), lane));
}

// ---------------- Kernel 0: bf16 weight prep ----------------
// w1b[jj][h] = w1[h][jj]  (128 x 64), w2b[h][jj] = w2[jj][h]  (64 x 128)
__global__ __launch_bounds__(256) void prep_kernel(
    const float* __restrict__ w1, const float* __restrict__ w2,
    unsigned short* __restrict__ w1b, unsigned short* __restrict__ w2b) {
  int i = blockIdx.x * 256 + threadIdx.x;  // 0..16383
  if (i < 8192) {
    int jj = i >> 6, h = i & 63;
    w1b[i] = f2bf(w1[h * 128 + jj]);
  } else {
    int k = i - 8192;
    int h = k >> 7, jj = k & 127;
    w2b[k] = f2bf(w2[jj * 64 + h]);
  }
}

// ---------------- Kernel 1: encoder via bf16 MFMA ----------------
// One wave per 64-token tile. GEMM1: D1[jj][tok] = w1b(A) x e(B);
// GEMM2: D2[tok][h] = act(A) x w2b(B). Residual/LN in f32 (e re-gathered f32).
__global__ __launch_bounds__(64, 1) void encoder_kernel(
    const int* __restrict__ seq, const float* __restrict__ embed,
    const unsigned short* __restrict__ w1b, const float* __restrict__ b1,
    const unsigned short* __restrict__ w2b, const float* __restrict__ b2,
    const float* __restrict__ ln_g, const float* __restrict__ ln_b,
    float* __restrict__ h_all, float* __restrict__ beta) {
  __shared__ __align__(16) unsigned short e_l[64][72];    // bf16 e tile [tok][h]
  __shared__ __align__(16) unsigned short act_l[64][136];  // bf16 act [tok][jj]
  __shared__ float x_l[64][65];                            // f32 f-part [tok][h]
  __shared__ float2 gb_l[64];
  __shared__ float b1_l[128], b2_l[64];

  int lane = threadIdx.x;
  int q = lane >> 4, l = lane & 15;
  int base = blockIdx.x * 64;
  int s = seq[base + lane];

  // stage e (f32 gather -> bf16 LDS), biases, ln params
  {
    const float4* ep = reinterpret_cast<const float4*>(embed + (size_t)s * HH);
#pragma unroll
    for (int i = 0; i < 8; ++i) {
      float4 va = ep[2 * i], vb = ep[2 * i + 1];
      uint4 u;
      u.x = (unsigned)f2bf(va.x) | ((unsigned)f2bf(va.y) << 16);
      u.y = (unsigned)f2bf(va.z) | ((unsigned)f2bf(va.w) << 16);
      u.z = (unsigned)f2bf(vb.x) | ((unsigned)f2bf(vb.y) << 16);
      u.w = (unsigned)f2bf(vb.z) | ((unsigned)f2bf(vb.w) << 16);
      *(uint4*)&e_l[lane][8 * i] = u;
    }
  }
  gb_l[lane] = make_float2(ln_g[lane], ln_b[lane]);
  b1_l[lane] = b1[lane];
  b1_l[64 + lane] = b1[64 + lane];
  b2_l[lane] = b2[lane];

  // A-frags of GEMM1 from global w1b: row jj = mi*16+l, cols ks*32+q*8
  bf16x8 af1[8][2];
#pragma unroll
  for (int mi = 0; mi < 8; ++mi)
#pragma unroll
    for (int ks = 0; ks < 2; ++ks) {
      U16x8 t;
      t.u = *(const uint4*)(w1b + (mi * 16 + l) * 64 + ks * 32 + q * 8);
      af1[mi][ks] = t.v;
    }

  __syncthreads();

  // ---- GEMM1: acc1[mi][nt] : D1[jj][tok]
  f32x4 acc1[8][4];
#pragma unroll
  for (int mi = 0; mi < 8; ++mi)
#pragma unroll
    for (int nt = 0; nt < 4; ++nt) acc1[mi][nt] = (f32x4){0.f, 0.f, 0.f, 0.f};

#pragma unroll
  for (int ks = 0; ks < 2; ++ks) {
    bf16x8 bfr[4];
#pragma unroll
    for (int nt = 0; nt < 4; ++nt) {
      U16x8 t;
      t.u = *(const uint4*)&e_l[nt * 16 + l][ks * 32 + q * 8];
      bfr[nt] = t.v;
    }
#pragma unroll
    for (int mi = 0; mi < 8; ++mi)
#pragma unroll
      for (int nt = 0; nt < 4; ++nt)
        acc1[mi][nt] = __builtin_amdgcn_mfma_f32_16x16x32_bf16(
            af1[mi][ks], bfr[nt], acc1[mi][nt], 0, 0, 0);
  }

  // bias + relu + pack -> act_l[tok][jj] (4 consecutive jj per lane = b64)
#pragma unroll
  for (int mi = 0; mi < 8; ++mi)
#pragma unroll
    for (int nt = 0; nt < 4; ++nt) {
      int tok = nt * 16 + l;
      int jj0 = mi * 16 + q * 4;
      float v0 = fmaxf(acc1[mi][nt][0] + b1_l[jj0 + 0], 0.f);
      float v1 = fmaxf(acc1[mi][nt][1] + b1_l[jj0 + 1], 0.f);
      float v2 = fmaxf(acc1[mi][nt][2] + b1_l[jj0 + 2], 0.f);
      float v3 = fmaxf(acc1[mi][nt][3] + b1_l[jj0 + 3], 0.f);
      uint2 u;
      u.x = (unsigned)f2bf(v0) | ((unsigned)f2bf(v1) << 16);
      u.y = (unsigned)f2bf(v2) | ((unsigned)f2bf(v3) << 16);
      *(uint2*)&act_l[tok][jj0] = u;
    }

  // B-frags of GEMM2 from global w2b: row h = nt*16+l, cols ks*32+q*8
  bf16x8 bf2[4][4];
#pragma unroll
  for (int nt = 0; nt < 4; ++nt)
#pragma unroll
    for (int ks = 0; ks < 4; ++ks) {
      U16x8 t;
      t.u = *(const uint4*)(w2b + (nt * 16 + l) * 128 + ks * 32 + q * 8);
      bf2[nt][ks] = t.v;
    }

  __syncthreads();

  // ---- GEMM2: acc2[mt][nt] : D2[tok][h]
  f32x4 acc2[4][4];
#pragma unroll
  for (int mt = 0; mt < 4; ++mt)
#pragma unroll
    for (int nt = 0; nt < 4; ++nt) acc2[mt][nt] = (f32x4){0.f, 0.f, 0.f, 0.f};

#pragma unroll
  for (int ks = 0; ks < 4; ++ks) {
    bf16x8 afr[4];
#pragma unroll
    for (int mt = 0; mt < 4; ++mt) {
      U16x8 t;
      t.u = *(const uint4*)&act_l[mt * 16 + l][ks * 32 + q * 8];
      afr[mt] = t.v;
    }
#pragma unroll
    for (int mt = 0; mt < 4; ++mt)
#pragma unroll
      for (int nt = 0; nt < 4; ++nt)
        acc2[mt][nt] = __builtin_amdgcn_mfma_f32_16x16x32_bf16(
            afr[mt], bf2[nt][ks], acc2[mt][nt], 0, 0, 0);
  }

  // write raw f (+b2) to x_l[tok][h]
#pragma unroll
  for (int mt = 0; mt < 4; ++mt)
#pragma unroll
    for (int nt = 0; nt < 4; ++nt) {
      int h = nt * 16 + l;
#pragma unroll
      for (int r = 0; r < 4; ++r) {
        int tok = mt * 16 + q * 4 + r;
        x_l[tok][h] = acc2[mt][nt][r] + b2_l[h];
      }
    }

  __syncthreads();

  // ---- epilogue: lane = token. x = f + e(f32); LN; store; beta.
  float x[HH];
#pragma unroll
  for (int h = 0; h < HH; ++h) x[h] = x_l[lane][h];
  {
    const float4* ep = reinterpret_cast<const float4*>(embed + (size_t)s * HH);
#pragma unroll
    for (int i = 0; i < 16; ++i) {
      float4 v = ep[i];
      x[4 * i + 0] += v.x; x[4 * i + 1] += v.y;
      x[4 * i + 2] += v.z; x[4 * i + 3] += v.w;
    }
  }
  float sum = 0.f;
#pragma unroll
  for (int h = 0; h < HH; ++h) sum += x[h];
  float mu = sum * (1.f / HH);
  float vs = 0.f;
#pragma unroll
  for (int h = 0; h < HH; ++h) { float dx = x[h] - mu; vs = fmaf(dx, dx, vs); }
  float rstd = rsqrtf(vs * (1.f / HH) + LN_EPS_F);

  float ss = 0.f;
#pragma unroll
  for (int h = 0; h < HH; ++h) {
    float2 gb = gb_l[h];  // uniform LDS broadcast
    float o = fmaf((x[h] - mu) * rstd, gb.x, gb.y);
    ss = fmaf(o, o, ss);
    x[h] = o;
  }
  float4* hp = reinterpret_cast<float4*>(h_all + (size_t)(base + lane) * HH);
#pragma unroll
  for (int i = 0; i < 16; ++i)
    hp[i] = make_float4(x[4 * i + 0], x[4 * i + 1], x[4 * i + 2], x[4 * i + 3]);
  beta[base + lane] = 1.f / (ss + DELTA_EPS_F);
}

// ---------------- Kernel 2 (phase 1): per-chunk transform matrices ----------------
// A_c = prod_t (I - beta_t k_t k_t^T), lane = column. k broadcast via UNIFORM
// LDS reads (free broadcast, no readlane hazards). Exact f32.
__global__ __launch_bounds__(64, 1) void chunk_mat_kernel(
    const float* __restrict__ h_all, const float* __restrict__ beta,
    float* __restrict__ A_g) {
  int c = blockIdx.x, b = blockIdx.y, lane = threadIdx.x;
  __shared__ __align__(16) float kl[64][72];
  __shared__ float bl[64];
  int q = lane >> 4, l = lane & 15;

  const float* src = h_all + ((size_t)b * LL + c * CS) * HH;
#pragma unroll
  for (int i = 0; i < 16; ++i) {
    int row = i * 4 + q;
    float4 v = *(const float4*)&src[row * 64 + l * 4];
    *(float4*)&kl[row][l * 4] = v;
  }
  bl[lane] = beta[(size_t)b * LL + c * CS + lane];
  if (c == NG - 1) kl[63][lane] = 0.f;  // t = L-1 is q's slot, not a key
  __syncthreads();

  float A[HH];
#pragma unroll
  for (int h = 0; h < HH; ++h) A[h] = (h == lane) ? 1.f : 0.f;

#pragma unroll 2
  for (int t = CS - 1; t >= 0; --t) {
    float4 k4[16];
#pragma unroll
    for (int i = 0; i < 16; ++i) k4[i] = *(const float4*)&kl[t][4 * i];  // uniform
    float d0 = 0.f, d1 = 0.f, d2 = 0.f, d3 = 0.f;
#pragma unroll
    for (int i = 0; i < 16; ++i) {
      d0 = fmaf(k4[i].x, A[4 * i + 0], d0);
      d1 = fmaf(k4[i].y, A[4 * i + 1], d1);
      d2 = fmaf(k4[i].z, A[4 * i + 2], d2);
      d3 = fmaf(k4[i].w, A[4 * i + 3], d3);
    }
    float bd = -bl[t] * ((d0 + d1) + (d2 + d3));
#pragma unroll
    for (int i = 0; i < 16; ++i) {
      A[4 * i + 0] = fmaf(bd, k4[i].x, A[4 * i + 0]);
      A[4 * i + 1] = fmaf(bd, k4[i].y, A[4 * i + 1]);
      A[4 * i + 2] = fmaf(bd, k4[i].z, A[4 * i + 2]);
      A[4 * i + 3] = fmaf(bd, k4[i].w, A[4 * i + 3]);
    }
  }

  float* Ag = A_g + ((size_t)b * NG + c) * HH * HH;
#pragma unroll
  for (int h = 0; h < HH; ++h) Ag[(size_t)h * HH + lane] = A[h];
}

// ---------------- Kernel 3 (phase 2): chunk-boundary propagation ----------------
__global__ __launch_bounds__(64, 1) void boundary_kernel(
    const float* __restrict__ h_all, const float* __restrict__ A_g,
    const int* __restrict__ read_pos_p, float* __restrict__ Qg) {
  int b = blockIdx.x, lane = threadIdx.x;
  int rpv = read_pos_p[0];
  int pos = rpv < 0 ? rpv + LL : rpv;

  float Q = h_all[((size_t)b * LL + pos) * HH + lane];

  const float* Ab = A_g + (size_t)b * NG * HH * HH + (size_t)lane * HH;

  float4 cur[16], nxt[16], nx2[16];
  {
    const float4* p = reinterpret_cast<const float4*>(Ab + (size_t)(NG - 1) * HH * HH);
#pragma unroll
    for (int i = 0; i < 16; ++i) cur[i] = p[i];
  }
  {
    const float4* p = reinterpret_cast<const float4*>(Ab + (size_t)(NG - 2) * HH * HH);
#pragma unroll
    for (int i = 0; i < 16; ++i) nxt[i] = p[i];
  }

#pragma unroll 1
  for (int c = NG - 1; c >= 0; --c) {
    if (c >= 2) {
      const float4* p = reinterpret_cast<const float4*>(Ab + (size_t)(c - 2) * HH * HH);
#pragma unroll
      for (int i = 0; i < 16; ++i) nx2[i] = p[i];
    }
    Qg[((size_t)b * NG + c) * HH + lane] = Q;
    float a0 = 0.f, a1 = 0.f, a2 = 0.f, a3 = 0.f;
#pragma unroll
    for (int i = 0; i < 16; ++i) {
      a0 = fmaf(readlane_f(Q, 4 * i + 0), cur[i].x, a0);
      a1 = fmaf(readlane_f(Q, 4 * i + 1), cur[i].y, a1);
      a2 = fmaf(readlane_f(Q, 4 * i + 2), cur[i].z, a2);
      a3 = fmaf(readlane_f(Q, 4 * i + 3), cur[i].w, a3);
    }
    Q = (a0 + a1) + (a2 + a3);
#pragma unroll
    for (int i = 0; i < 16; ++i) { cur[i] = nxt[i]; nxt[i] = nx2[i]; }
  }
}

// ---------------- Kernel 4 (phase 3): parallel within-chunk r accumulation -------
__global__ __launch_bounds__(64, 1) void chunk_scan_kernel(
    const float* __restrict__ h_all, const float* __restrict__ beta,
    const float* __restrict__ Qg, float* __restrict__ rc) {
  int c = blockIdx.x, b = blockIdx.y, j = threadIdx.x;
  const float* hb = h_all + (size_t)b * LL * HH;
  const float* betab = beta + (size_t)b * LL;

  float P = Qg[((size_t)b * NG + c) * HH + j];
  float r = 0.f;

  float kk[CS];
#pragma unroll
  for (int i = 0; i < CS; ++i) kk[i] = hb[((size_t)(c * CS + i)) * HH + j];
  float bv = betab[c * CS + j];

  bool last = (c == NG - 1);
#pragma unroll
  for (int i = CS - 1; i >= 0; --i) {
    float k = kk[i];
    float bt = readlane_f(bv, i);
    float m = k * P;
    float s = wave_sum_lane63(m);
    float d = readlane_f(s, 63);
    if (i == CS - 1 && last) d = 0.f;
    r = fmaf(d, k, r);
    P = fmaf(-(bt * d), k, P);
  }
  rc[((size_t)b * NG + c) * HH + j] = r;
}

// ---------------- Kernel 5: combine r over chunks, y = r @ rp_w + rp_b ----------
__global__ __launch_bounds__(64, 1) void combine_kernel(
    const float* __restrict__ rc, const float* __restrict__ rp_w,
    const float* __restrict__ rp_b, float* __restrict__ yv) {
  int b = blockIdx.x, j = threadIdx.x;
  float r = 0.f;
#pragma unroll 8
  for (int cc = 0; cc < NG; ++cc) r += rc[((size_t)b * NG + cc) * HH + j];
  __shared__ float rs[HH];
  rs[j] = r;
  __syncthreads();
  float yj = rp_b[j];
#pragma unroll
  for (int h = 0; h < HH; ++h) yj = fmaf(rs[h], rp_w[h * HH + j], yj);
  yv[b * HH + j] = yj;
}

// ---------------- Kernel 6: output GEMM ----------------
__global__ __launch_bounds__(256, 2) void out_kernel(
    const float* __restrict__ yv, const float* __restrict__ out_w,
    const float* __restrict__ out_b, float* __restrict__ out) {
  __shared__ float ys[BB * HH];
  for (int i = threadIdx.x; i < BB * HH; i += 256) ys[i] = yv[i];
  __syncthreads();

  int v = blockIdx.x * 256 + threadIdx.x;
  if (v >= VV) return;

  float acc[BB];
  float ob = out_b[v];
#pragma unroll
  for (int b = 0; b < BB; ++b) acc[b] = ob;

  for (int h = 0; h < HH; ++h) {
    float w = out_w[(size_t)h * VV + v];
#pragma unroll
    for (int b = 0; b < BB; ++b) acc[b] = fmaf(ys[b * HH + h], w, acc[b]);
  }
#pragma unroll
  for (int b = 0; b < BB; ++b) out[(size_t)b * VV + v] = acc[b];
}

// ---------------- launch ----------------
extern "C" void kernel_launch(void* const* d_in, const int* in_sizes, int n_in,
                              void* d_out, int out_size, void* d_ws, size_t ws_size,
                              hipStream_t stream) {
  (void)in_sizes; (void)n_in; (void)out_size; (void)ws_size;
  const int*   seq   = (const int*)d_in[0];
  const int*   rp    = (const int*)d_in[1];
  const float* embed = (const float*)d_in[2];
  const float* w1    = (const float*)d_in[3];
  const float* b1    = (const float*)d_in[4];
  const float* w2    = (const float*)d_in[5];
  const float* b2    = (const float*)d_in[6];
  const float* ln_g  = (const float*)d_in[7];
  const float* ln_b  = (const float*)d_in[8];
  const float* rp_w  = (const float*)d_in[9];
  const float* rp_b  = (const float*)d_in[10];
  const float* out_w = (const float*)d_in[11];
  const float* out_b = (const float*)d_in[12];
  float* out = (float*)d_out;

  // workspace layout (~68.6 MB)
  float* h_all = (float*)d_ws;                               // B*L*H
  float* beta  = h_all + (size_t)BB * LL * HH;               // B*L
  float* A_g   = beta + (size_t)BB * LL;                     // B*NG*H*H
  float* Qg    = A_g + (size_t)BB * NG * HH * HH;            // B*NG*H
  float* rcv   = Qg + (size_t)BB * NG * HH;                  // B*NG*H
  float* yv    = rcv + (size_t)BB * NG * HH;                 // B*H
  unsigned short* w1b = (unsigned short*)(yv + (size_t)BB * HH);  // 128*64 bf16
  unsigned short* w2b = w1b + 8192;                               // 64*128 bf16

  prep_kernel<<<64, 256, 0, stream>>>(w1, w2, w1b, w2b);
  encoder_kernel<<<BB * LL / 64, 64, 0, stream>>>(seq, embed, w1b, b1, w2b, b2,
                                                  ln_g, ln_b, h_all, beta);
  chunk_mat_kernel<<<dim3(NG, BB), 64, 0, stream>>>(h_all, beta, A_g);
  boundary_kernel<<<BB, 64, 0, stream>>>(h_all, A_g, rp, Qg);
  chunk_scan_kernel<<<dim3(NG, BB), 64, 0, stream>>>(h_all, beta, Qg, rcv);
  combine_kernel<<<BB, 64, 0, stream>>>(rcv, rp_w, rp_b, yv);
  out_kernel<<<(VV + 255) / 256, 256, 0, stream>>>(yv, out_w, out_b, out);
}